// Round 1
// baseline (28.395 us; speedup 1.0000x reference)
//
#include <hip/hip_runtime.h>
#include <stdint.h>

typedef __attribute__((ext_vector_type(8))) short short8;   // 8 x bf16 bits
typedef __attribute__((ext_vector_type(4))) float f32x4;
typedef __attribute__((ext_vector_type(2))) float f32x2;
typedef unsigned long long u64;

// Problem constants (from reference): R=C=64, D=128, B=256, RC=4096
// sigma/alpha are read from device inputs at runtime.

static __device__ __forceinline__ unsigned short f2bf(float f) {
    // fp32 -> bf16 round-to-nearest-even
    uint32_t u = __float_as_uint(f);
    uint32_t r = (u + 0x7FFFu + ((u >> 16) & 1u)) >> 16;
    return (unsigned short)r;
}

// ---------------------------------------------------------------------------
// K0: convert w -> wb (bf16), compute wn2[n] = ||w_n||^2 (fp32),
//     convert x -> xb [256][128] bf16 AND xbT [128][256] bf16 (transposed).
// grid = 272 blocks x 256 thr: blocks 0..255 handle 16 w-rows each,
// blocks 256..271 handle 16 x-rows each.
// ---------------------------------------------------------------------------
__global__ __launch_bounds__(256) void k_prep(
    const float* __restrict__ x, const float* __restrict__ w,
    unsigned short* __restrict__ xb, unsigned short* __restrict__ xbT,
    unsigned short* __restrict__ wb, float* __restrict__ wn2)
{
    const int bid = blockIdx.x, tid = threadIdx.x;
    const int sub = tid & 15;     // 16 chunks of 8 floats per 128-row
    const int rloc = tid >> 4;    // 16 rows per block

    if (bid < 256) {
        const int row = bid * 16 + rloc;              // neuron 0..4095
        const float* src = w + row * 128 + sub * 8;
        f32x4 v0 = *reinterpret_cast<const f32x4*>(src);
        f32x4 v1 = *reinterpret_cast<const f32x4*>(src + 4);
        float sq = v0[0]*v0[0] + v0[1]*v0[1] + v0[2]*v0[2] + v0[3]*v0[3]
                 + v1[0]*v1[0] + v1[1]*v1[1] + v1[2]*v1[2] + v1[3]*v1[3];
        short8 pk;
        #pragma unroll
        for (int i = 0; i < 4; ++i) pk[i] = (short)f2bf(v0[i]);
        #pragma unroll
        for (int i = 0; i < 4; ++i) pk[4 + i] = (short)f2bf(v1[i]);
        *reinterpret_cast<short8*>(wb + row * 128 + sub * 8) = pk;
        // reduce ||w||^2 across the 16 lanes covering this row
        sq += __shfl_xor(sq, 1);
        sq += __shfl_xor(sq, 2);
        sq += __shfl_xor(sq, 4);
        sq += __shfl_xor(sq, 8);
        if (sub == 0) wn2[row] = sq;
    } else {
        const int row = (bid - 256) * 16 + rloc;      // batch 0..255
        const float* src = x + row * 128 + sub * 8;
        f32x4 v0 = *reinterpret_cast<const f32x4*>(src);
        f32x4 v1 = *reinterpret_cast<const f32x4*>(src + 4);
        short8 pk;
        #pragma unroll
        for (int i = 0; i < 4; ++i) pk[i] = (short)f2bf(v0[i]);
        #pragma unroll
        for (int i = 0; i < 4; ++i) pk[4 + i] = (short)f2bf(v1[i]);
        *reinterpret_cast<short8*>(xb + row * 128 + sub * 8) = pk;
        // transposed copy for the update GEMM's B-operand (k = batch contiguous)
        #pragma unroll
        for (int i = 0; i < 8; ++i)
            xbT[(sub * 8 + i) * 256 + row] = (unsigned short)pk[i];
    }
}

// ---------------------------------------------------------------------------
// K1: BMU search. dot(b,n) via mfma_f32_16x16x32_bf16; key = 0.5*||w||^2 - dot.
// grid = 256 blocks (4 b-tiles of 64 x 64 n-tiles of 64), 4 waves/block.
// Fragments read directly from global (L2-hot, no LDS). Per-wave packed-u64
// shfl argmin over 16 col-lanes, then atomicMin into bmuKey[b].
// key packing: monotone-unsigned(float) << 32 | n  -> ties pick lowest n,
// matching jnp.argmin first-min semantics.
// ---------------------------------------------------------------------------
__global__ __launch_bounds__(256) void k_bmu(
    const unsigned short* __restrict__ xb, const unsigned short* __restrict__ wb,
    const float* __restrict__ wn2, u64* __restrict__ bmuKey)
{
    const int tid = threadIdx.x;
    const int wv = tid >> 6, l = tid & 63;
    const int c = l & 15, kg = l >> 4;
    const int bt = blockIdx.x & 3, nt = blockIdx.x >> 2;
    const int b0 = bt * 64 + wv * 16;   // this wave's 16 batch rows
    const int n0 = nt * 64;             // this block's 64 neurons

    // A fragments: x rows (m = batch). lane: row = l&15, k = (l>>4)*8 + i
    short8 a[4];
    #pragma unroll
    for (int ks = 0; ks < 4; ++ks)
        a[ks] = *reinterpret_cast<const short8*>(
            xb + (b0 + c) * 128 + ks * 32 + kg * 8);

    f32x4 acc[4];
    #pragma unroll
    for (int nf = 0; nf < 4; ++nf) acc[nf] = (f32x4){0.f, 0.f, 0.f, 0.f};

    #pragma unroll
    for (int ks = 0; ks < 4; ++ks) {
        #pragma unroll
        for (int nf = 0; nf < 4; ++nf) {
            short8 bfr = *reinterpret_cast<const short8*>(
                wb + (n0 + nf * 16 + c) * 128 + ks * 32 + kg * 8);
            acc[nf] = __builtin_amdgcn_mfma_f32_16x16x32_bf16(a[ks], bfr, acc[nf], 0, 0, 0);
        }
    }

    float wn2v[4];
    #pragma unroll
    for (int nf = 0; nf < 4; ++nf) wn2v[nf] = wn2[n0 + nf * 16 + c];

    // C/D layout: col = lane&15 (n), row = (lane>>4)*4 + reg (b)
    #pragma unroll
    for (int j = 0; j < 4; ++j) {
        u64 best = 0xFFFFFFFFFFFFFFFFull;
        #pragma unroll
        for (int nf = 0; nf < 4; ++nf) {
            float keyf = 0.5f * wn2v[nf] - acc[nf][j];
            uint32_t u = __float_as_uint(keyf);
            u = ((int)u >= 0) ? (u | 0x80000000u) : ~u;   // monotone unsigned
            u64 pk = ((u64)u << 32) | (u64)(n0 + nf * 16 + c);
            best = (pk < best) ? pk : best;
        }
        #pragma unroll
        for (int m = 1; m < 16; m <<= 1) {
            u64 o = __shfl_xor(best, m);
            best = (o < best) ? o : best;
        }
        if (c == 0) atomicMin(bmuKey + (b0 + kg * 4 + j), best);
    }
}

// ---------------------------------------------------------------------------
// K2: update. Per block: 16 neurons. Phase 0: decode all 256 BMUs into LDS.
// Phase 1: gT[16][256] bf16 in LDS (padded stride 264) + S[n] -> coef[n].
// Phase 2: T = gT x xbT via mfma (M=16 n, N=128 d, K=256 b), each wave owns
// a 32-wide d-slice. Epilogue: out = w*coef + (alpha/B)*T.
// ---------------------------------------------------------------------------
__global__ __launch_bounds__(256) void k_update(
    const unsigned short* __restrict__ xbT, const float* __restrict__ w,
    const u64* __restrict__ bmuKey, const float* __restrict__ alpha_p,
    const float* __restrict__ sigma_p, float* __restrict__ out)
{
    __shared__ f32x2 rc_lds[256];
    __shared__ unsigned short gT[16][264];   // +8 pad: 528B stride -> 2-way banks (free)
    __shared__ float coef_lds[16];

    const int tid = threadIdx.x;
    const int n0 = blockIdx.x * 16;
    const float alpha = alpha_p[0];
    const float sigma = sigma_p[0];
    const float inv_s2 = 1.0f / (sigma * sigma);
    const float aB = alpha * (1.0f / 256.0f);

    // phase 0: decode BMU grid coords for every batch element
    {
        u64 kv = bmuKey[tid];
        int idx = (int)(uint32_t)(kv & 0xFFFFFFFFull);
        f32x2 rc;
        rc[0] = (float)(idx >> 6);
        rc[1] = (float)(idx & 63);
        rc_lds[tid] = rc;
    }
    __syncthreads();

    // phase 1: gaussian neighborhood, bf16 Gt tile + row sums
    {
        const int nl = tid >> 4, bq = tid & 15;
        const int n = n0 + nl;
        const float nr = (float)(n >> 6), nc = (float)(n & 63);
        float s = 0.f;
        #pragma unroll
        for (int j = 0; j < 16; ++j) {
            const int b = bq + 16 * j;
            f32x2 rc = rc_lds[b];
            float dr = rc[0] - nr, dc = rc[1] - nc;
            float g = __expf(-(dr * dr + dc * dc) * inv_s2);
            s += g;
            gT[nl][b] = f2bf(g);
        }
        s += __shfl_xor(s, 1);
        s += __shfl_xor(s, 2);
        s += __shfl_xor(s, 4);
        s += __shfl_xor(s, 8);
        if (bq == 0) coef_lds[nl] = 1.0f - aB * s;   // 1 - (a/B)*S[n]
    }
    __syncthreads();

    // phase 2: T[n][d] = sum_b gT[n][b] * x[b][d] via MFMA, fused epilogue
    const int wv = tid >> 6, l = tid & 63;
    const int c = l & 15, kg = l >> 4;
    f32x4 acc[2];
    acc[0] = (f32x4){0.f, 0.f, 0.f, 0.f};
    acc[1] = (f32x4){0.f, 0.f, 0.f, 0.f};

    #pragma unroll
    for (int ks = 0; ks < 8; ++ks) {
        short8 a = *reinterpret_cast<const short8*>(&gT[c][ks * 32 + kg * 8]);
        #pragma unroll
        for (int nf = 0; nf < 2; ++nf) {
            const int d = wv * 32 + nf * 16 + c;
            short8 bfr = *reinterpret_cast<const short8*>(
                xbT + d * 256 + ks * 32 + kg * 8);
            acc[nf] = __builtin_amdgcn_mfma_f32_16x16x32_bf16(a, bfr, acc[nf], 0, 0, 0);
        }
    }

    #pragma unroll
    for (int nf = 0; nf < 2; ++nf) {
        #pragma unroll
        for (int j = 0; j < 4; ++j) {
            const int nloc = kg * 4 + j;                 // C row = n-local
            const int d = wv * 32 + nf * 16 + c;         // C col = d
            const int gi = (n0 + nloc) * 128 + d;
            out[gi] = w[gi] * coef_lds[nloc] + aB * acc[nf][j];
        }
    }
}

// ---------------------------------------------------------------------------
extern "C" void kernel_launch(void* const* d_in, const int* in_sizes, int n_in,
                              void* d_out, int out_size, void* d_ws, size_t ws_size,
                              hipStream_t stream) {
    const float* x     = (const float*)d_in[0];   // [256][128]
    const float* w     = (const float*)d_in[1];   // [64][64][128]
    const float* alpha = (const float*)d_in[2];
    const float* sigma = (const float*)d_in[3];
    float* out = (float*)d_out;

    char* ws = (char*)d_ws;
    u64*            bmuKey = (u64*)(ws);                      // 2 KB
    float*          wn2    = (float*)(ws + 2048);             // 16 KB
    unsigned short* xb     = (unsigned short*)(ws + 32768);   // 64 KB
    unsigned short* xbT    = (unsigned short*)(ws + 98304);   // 64 KB
    unsigned short* wb     = (unsigned short*)(ws + 163840);  // 1 MB
    // total ws use: ~1.16 MB

    hipMemsetAsync(bmuKey, 0xFF, 256 * sizeof(u64), stream);
    k_prep<<<272, 256, 0, stream>>>(x, w, xb, xbT, wb, wn2);
    k_bmu<<<256, 256, 0, stream>>>(xb, wb, wn2, bmuKey);
    k_update<<<256, 256, 0, stream>>>(xbT, w, bmuKey, alpha, sigma, out);
}